// Round 14
// baseline (214.672 us; speedup 1.0000x reference)
//
#include <hip/hip_runtime.h>

#define UNITS 4096
#define DEPTH 13
#define BATCH 256

typedef __attribute__((ext_vector_type(8))) short s16x8;
typedef __attribute__((ext_vector_type(4))) float f32x4;
typedef __attribute__((ext_vector_type(4))) int   i32x4;

__device__ __forceinline__ unsigned short f2bf(float f){
  unsigned u = __builtin_bit_cast(unsigned, f);
  u += 0x7FFFu + ((u >> 16) & 1u);
  return (unsigned short)(u >> 16);
}
__device__ __forceinline__ int levelof(int j){ return j ? (32 - __clz(j)) : 0; }

struct FragA { s16x8 v[2]; };      // 8 VGPR: M=16 rows x K=64
struct FragB { s16x8 v[2][4]; };   // 32 VGPR: N=64 x K=64

// async global->LDS, 16B per lane, wave-uniform LDS base (+ lane*16 implicit)
__device__ __forceinline__ void gll16(const void* g, void* l){
  __builtin_amdgcn_global_load_lds(
      (const __attribute__((address_space(1))) unsigned int*)g,
      (__attribute__((address_space(3))) unsigned int*)l, 16, 0, 0);
}

// global-direct frag loads (q==0 path only)
__device__ __forceinline__ void load_afragG(FragA& f, const unsigned short* __restrict__ Hq,
                                            int rowbase, int l15, int kg){
  #pragma unroll
  for (int kk = 0; kk < 2; ++kk)
    f.v[kk] = *(const s16x8*)(Hq + ((size_t)((kk*4 + kg)*256 + rowbase + l15))*8);
}
__device__ __forceinline__ void load_bfragG(FragB& f, const unsigned short* __restrict__ Wf,
                                            int lane){
  #pragma unroll
  for (int kk = 0; kk < 2; ++kk)
    #pragma unroll
    for (int n = 0; n < 4; ++n)
      f.v[kk][n] = *(const s16x8*)(Wf + ((size_t)((kk*4 + n)*64 + lane))*8);
}
// LDS frag loads (A slice: [piece][64 rows]*16B; B: W2f layout)
__device__ __forceinline__ void ld_afragL(FragA& f, const char* Ab, int wid, int l15, int kg){
  #pragma unroll
  for (int kk = 0; kk < 2; ++kk)
    f.v[kk] = *(const s16x8*)(Ab + (kk*4 + kg)*1024 + (wid*16 + l15)*16);
}
__device__ __forceinline__ void ld_bfragL(FragB& f, const char* Bb, int lane){
  #pragma unroll
  for (int kk = 0; kk < 2; ++kk)
    #pragma unroll
    for (int n = 0; n < 4; ++n)
      f.v[kk][n] = *(const s16x8*)(Bb + ((kk*4 + n)*64 + lane)*16);
}
__device__ __forceinline__ void mstep(f32x4 acc[4], const FragA& A, const FragB& B){
  #pragma unroll
  for (int kk = 0; kk < 2; ++kk)
    #pragma unroll
    for (int n = 0; n < 4; ++n)
      acc[n] = __builtin_amdgcn_mfma_f32_16x16x32_bf16(A.v[kk], B.v[kk][n], acc[n], 0, 0, 0);
}
__device__ __forceinline__ void negA(FragA& A){
  const i32x4 sgn = {(int)0x80008000, (int)0x80008000, (int)0x80008000, (int)0x80008000};
  #pragma unroll
  for (int kk = 0; kk < 2; ++kk){
    i32x4 t = __builtin_bit_cast(i32x4, A.v[kk]);
    t ^= sgn;
    A.v[kk] = __builtin_bit_cast(s16x8, t);
  }
}

// MFMA epilogue: d{0,1} += W3(2 M-tiles) . relu(acc+cbv).
// h2 packed bf16 into per-wave LDS scratch (XOR-by-(brow>>2)=kg swizzle),
// read back as B-frags (brow=l15, feats kg*8+e per kk). No global stores here.
__device__ __forceinline__ void epi_mfma(const f32x4 acc[4], const float cbv[4],
    char* scr, const s16x8 (&w3a)[2][2], f32x4& d0, f32x4& d1,
    int l15, int kg){
  #pragma unroll
  for (int n = 0; n < 4; ++n)
    #pragma unroll
    for (int reg = 0; reg < 4; ++reg){
      float hv = fmaxf(acc[n][reg] + cbv[n], 0.f);
      int a16 = (kg*4 + reg)*64 + ((n*16 + l15) ^ (kg << 4));
      *(unsigned short*)(scr + a16*2) = f2bf(hv);
    }
  int key = (l15 >> 2) << 4;
  s16x8 b0 = *(const s16x8*)(scr + (size_t)(l15*64 + ((kg*8)      ^ key))*2);
  s16x8 b1 = *(const s16x8*)(scr + (size_t)(l15*64 + ((32 + kg*8) ^ key))*2);
  d0 = __builtin_amdgcn_mfma_f32_16x16x32_bf16(w3a[0][0], b0, d0, 0, 0, 0);
  d0 = __builtin_amdgcn_mfma_f32_16x16x32_bf16(w3a[1][0], b1, d0, 0, 0, 0);
  d1 = __builtin_amdgcn_mfma_f32_16x16x32_bf16(w3a[0][1], b0, d1, 0, 0, 0);
  d1 = __builtin_amdgcn_mfma_f32_16x16x32_bf16(w3a[1][1], b1, d1, 0, 0, 0);
}

// ---------------- K0: prep: W2f, W1f, W3 A-frags, cumulative biases ----------
__global__ __launch_bounds__(256) void k_prep(const float* __restrict__ W2,
    const float* __restrict__ W1, const float* __restrict__ W3,
    const float* __restrict__ b1, const float* __restrict__ b2, const float* __restrict__ b3,
    unsigned short* __restrict__ W2f, unsigned short* __restrict__ W1f,
    unsigned short* __restrict__ W3Af,
    float* __restrict__ cb1, float* __restrict__ cb2, float* __restrict__ cb3,
    float* __restrict__ w3h20){
  int blk = blockIdx.x, t = threadIdx.x;
  if (blk < 26){
    int u = blk*256 + t;
    int lane = u & 63, c = (u >> 6) & 7, k = u >> 9;
    int n = c & 3, kk = c >> 2, l15 = lane & 15, kg = lane >> 4;
    s16x8 rr;
    #pragma unroll
    for (int e = 0; e < 8; ++e)
      rr[e] = (short)f2bf(W2[((size_t)(k*64 + n*16 + l15))*64 + kk*32 + kg*8 + e]);
    *(s16x8*)(W2f + (size_t)u*8) = rr;
  } else if (blk == 26){
    int n = t >> 6, lane = t & 63, l15 = lane & 15, kg = lane >> 4;
    int f = n*16 + l15;
    s16x8 r = {0,0,0,0,0,0,0,0};
    #pragma unroll
    for (int j = 0; j < 4; ++j){
      int m = kg*4 + j;
      if (m < DEPTH-1){
        r[2*j]   = (short)f2bf(W1[(m*64 + f)*2]);
        r[2*j+1] = (short)f2bf(W1[(m*64 + f)*2 + 1]);
      }
    }
    *(s16x8*)(W1f + (size_t)t*8) = r;
  } else if (blk == 27){
    // W3 A-frags: row = tt' = tile*16 + l15 (0..25, zero-pad), k = kk*32+kg*8+e
    int lane = t & 63, tile = (t >> 6) & 1, kk = t >> 7;
    int l15 = lane & 15, kg = lane >> 4;
    int row = tile*16 + l15;
    s16x8 r = {0,0,0,0,0,0,0,0};
    if (row < 26){
      #pragma unroll
      for (int e = 0; e < 8; ++e)
        r[e] = (short)f2bf(W3[(size_t)row*64 + kk*32 + kg*8 + e]);
    }
    *(s16x8*)(W3Af + (size_t)t*8) = r;   // idx = ((kk*2+tile)*64 + lane)
  } else {
    if (t < 64){
      float r = 0.f;
      cb1[t] = 0.f;
      for (int m = 1; m < DEPTH; ++m){ r += b1[(m-1)*64 + t]; cb1[m*64 + t] = r; }
      float r2 = 0.f;
      for (int m = 0; m < DEPTH; ++m){ r2 += b2[m*64 + t]; cb2[m*64 + t] = r2; }
    } else if (t < 66){
      int o = t - 64;
      float r = 0.f;
      for (int m = 0; m < DEPTH; ++m){ r += b3[m*2 + o]; cb3[m*2 + o] = r; }
    } else if (t >= 128 && t < 128 + DEPTH*2){
      int q = t - 128, tt = q >> 1, o = q & 1;
      float s = 0.f;
      for (int f = 0; f < 64; ++f)
        s = fmaf(W3[(tt*2 + o)*64 + f], fmaxf(b2[f], 0.f), s);
      w3h20[tt*2 + o] = s;
    }
  }
}

// ---------------- K0b: transpose x[b][j][2] -> xT[j][b][2] -------------------
__global__ __launch_bounds__(256) void k_xpose(const float* __restrict__ x,
                                               float* __restrict__ xT){
  __shared__ float2 tile[64][65];
  int jb = (blockIdx.x & 63) * 64;
  int bb = (blockIdx.x >> 6) * 64;
  int t = threadIdx.x;
  #pragma unroll
  for (int i = 0; i < 16; ++i){
    int idx = i*256 + t;
    int jj = idx & 63, b = idx >> 6;
    tile[jj][b] = *(const float2*)(x + (((size_t)(bb + b))*UNITS + jb + jj)*2);
  }
  __syncthreads();
  #pragma unroll
  for (int i = 0; i < 16; ++i){
    int idx = i*256 + t;
    int b = idx & 63, jj = idx >> 6;
    *(float2*)(xT + (((size_t)(jb + jj))*BATCH + bb + b)*2) = tile[jj][b];
  }
}

// ---------------- K1: H[p] = relu(sum_m W1[m].x[p>>m] + cb1[lvl(p)+1]) -------
__global__ __launch_bounds__(256) void k_GH(const float* __restrict__ xT,
    const unsigned short* __restrict__ W1f, const float* __restrict__ cb1,
    unsigned short* __restrict__ H){
  __shared__ unsigned short tile[BATCH*64];
  int p = blockIdx.x;
  int lvl = levelof(p);
  int t = threadIdx.x, wid = t >> 6, lane = t & 63, l15 = lane & 15, kg = lane >> 4;

  s16x8 af[4];
  #pragma unroll
  for (int m = 0; m < 4; ++m){
    int b = wid*64 + m*16 + l15;
    s16x8 r = {0,0,0,0,0,0,0,0};
    #pragma unroll
    for (int j = 0; j < 4; ++j){
      int mm = kg*4 + j;
      if (mm <= lvl){
        float2 xv = *(const float2*)(xT + ((size_t)(p >> mm)*BATCH + b)*2);
        r[2*j]   = (short)f2bf(xv.x);
        r[2*j+1] = (short)f2bf(xv.y);
      }
    }
    af[m] = r;
  }
  f32x4 acc[4][4];
  #pragma unroll
  for (int m = 0; m < 4; ++m)
    #pragma unroll
    for (int n = 0; n < 4; ++n) acc[m][n] = (f32x4){0.f,0.f,0.f,0.f};
  #pragma unroll
  for (int n = 0; n < 4; ++n){
    s16x8 bf = *(const s16x8*)(W1f + ((size_t)n*64 + lane)*8);
    #pragma unroll
    for (int m = 0; m < 4; ++m)
      acc[m][n] = __builtin_amdgcn_mfma_f32_16x16x32_bf16(af[m], bf, acc[m][n], 0, 0, 0);
  }
  int lvl1 = lvl + 1;
  float cbv[4];
  #pragma unroll
  for (int n = 0; n < 4; ++n) cbv[n] = cb1[lvl1*64 + n*16 + l15];
  #pragma unroll
  for (int m = 0; m < 4; ++m)
    #pragma unroll
    for (int n = 0; n < 4; ++n)
      #pragma unroll
      for (int i = 0; i < 4; ++i){
        int row = wid*64 + m*16 + kg*4 + i;
        int col = n*16 + l15;
        float v = fmaxf(acc[m][n][i] + cbv[n], 0.f);
        *(unsigned short*)((char*)tile + ((row*128 + col*2) ^ ((row & 7) << 4))) = f2bf(v);
      }
  __syncthreads();
  #pragma unroll
  for (int i = 0; i < 8; ++i){
    s16x8 v = *(const s16x8*)((const char*)tile + ((t*128 + i*16) ^ ((t & 7) << 4)));
    *(s16x8*)(H + (size_t)p*16384 + ((size_t)i*256 + t)*8) = v;
  }
}

// ---------------- K2: quad-DFS F, LDS ring + MFMA epilogue, deferred stores --
#define STORE_D(dv0, dv1, pp, lpv) { \
  int cnt = 2*(12 - (lpv)); \
  _Pragma("unroll") \
  for (int tile_ = 0; tile_ < 2; ++tile_){ \
    _Pragma("unroll") \
    for (int reg_ = 0; reg_ < 4; ++reg_){ \
      int ttp = tile_*16 + kg*4 + reg_; \
      if (ttp < cnt){ \
        int tt = ttp >> 1, o = ttp & 1; \
        int offp = 4096 - (4096 >> tt); \
        y3[((size_t)(offp + (pp))*256 + rowbase + l15)*2 + o] = (tile_ ? (dv1)[reg_] : (dv0)[reg_]); \
      } \
    } \
  } }

__global__ __launch_bounds__(256, 3) void k_F12(const unsigned short* __restrict__ H,
    const unsigned short* __restrict__ W2f, const unsigned short* __restrict__ W3Af,
    const float* __restrict__ cb2, float* __restrict__ y3){
  __shared__ char As[2*8192];
  __shared__ char Bs[2*8192];
  __shared__ char scr_all[4*2048];

  int bid = blockIdx.x;
  int slice = bid >> 9;                // 0..3 (64 batch rows each)
  int r = bid & 511;
  int q = 511 - ((r & 7)*64 + (r >> 3));   // deep-first, XCD-contiguous
  int t = threadIdx.x, wid = t >> 6, lane = t & 63, l15 = lane & 15, kg = lane >> 4;
  int rowbase = slice*64 + wid*16;
  char* scr = scr_all + wid*2048;

  const char* Hb   = (const char*)H;
  const char* W2fb = (const char*)W2f;

  // W3 A-frags (held in registers)
  s16x8 w3a[2][2];
  #pragma unroll
  for (int kk = 0; kk < 2; ++kk)
    #pragma unroll
    for (int tile = 0; tile < 2; ++tile)
      w3a[kk][tile] = *(const s16x8*)(W3Af + ((size_t)((kk*2 + tile)*64 + lane))*8);

  f32x4 acc[4];
  #pragma unroll
  for (int n = 0; n < 4; ++n) acc[n] = (f32x4){0.f, 0.f, 0.f, 0.f};

  f32x4 dA0 = {0,0,0,0}, dA1 = {0,0,0,0}, dB0 = {0,0,0,0}, dB1 = {0,0,0,0};
  f32x4 dC0 = {0,0,0,0}, dC1 = {0,0,0,0}, dD0 = {0,0,0,0}, dD1 = {0,0,0,0};

  if (q == 0){
    FragA A; FragB B;
    float cbv[4];
    #pragma unroll
    for (int n = 0; n < 4; ++n) acc[n] = (f32x4){0.f, 0.f, 0.f, 0.f};
    // p = 0 (lp=0)
    { int lp = 0;
      #pragma unroll
      for (int n = 0; n < 4; ++n) cbv[n] = cb2[(lp+1)*64 + n*16 + l15];
      load_bfragG(B, W2f, lane);
      load_afragG(A, H, rowbase, l15, kg);
      mstep(acc, A, B);
      epi_mfma(acc, cbv, scr, w3a, dA0, dA1, l15, kg); }
    // p = 1 (lp=1)
    { int lp = 1;
      #pragma unroll
      for (int n = 0; n < 4; ++n){ cbv[n] = cb2[(lp+1)*64 + n*16 + l15]; acc[n] = (f32x4){0.f,0.f,0.f,0.f}; }
      for (int k = 0; k <= 1; ++k){
        load_bfragG(B, W2f + (size_t)k*4096, lane);
        load_afragG(A, H + (size_t)(1 >> k)*16384, rowbase, l15, kg);
        mstep(acc, A, B);
      }
      epi_mfma(acc, cbv, scr, w3a, dB0, dB1, l15, kg); }
    // p = 2 (lp=2)
    { int lp = 2;
      #pragma unroll
      for (int n = 0; n < 4; ++n){ cbv[n] = cb2[(lp+1)*64 + n*16 + l15]; acc[n] = (f32x4){0.f,0.f,0.f,0.f}; }
      for (int k = 0; k <= 2; ++k){
        load_bfragG(B, W2f + (size_t)k*4096, lane);
        load_afragG(A, H + (size_t)(2 >> k)*16384, rowbase, l15, kg);
        mstep(acc, A, B);
      }
      epi_mfma(acc, cbv, scr, w3a, dC0, dC1, l15, kg); }
    // p = 3 (lp=2)
    { int lp = 2;
      #pragma unroll
      for (int n = 0; n < 4; ++n){ cbv[n] = cb2[(lp+1)*64 + n*16 + l15]; acc[n] = (f32x4){0.f,0.f,0.f,0.f}; }
      for (int k = 0; k <= 2; ++k){
        load_bfragG(B, W2f + (size_t)k*4096, lane);
        load_afragG(A, H + (size_t)(3 >> k)*16384, rowbase, l15, kg);
        mstep(acc, A, B);
      }
      epi_mfma(acc, cbv, scr, w3a, dD0, dD1, l15, kg); }
    STORE_D(dA0, dA1, 0, 0)
    STORE_D(dB0, dB1, 1, 1)
    STORE_D(dC0, dC1, 2, 2)
    STORE_D(dD0, dD1, 3, 2)
    return;
  }

  const int L = levelof(q) + 2;        // leaf level, 2..11
  const int S = L + 5;                 // (L-1) chain steps + 6 DFS steps
  float cbv[4];
  #pragma unroll
  for (int n = 0; n < 4; ++n) cbv[n] = cb2[(L+1)*64 + n*16 + l15];

  auto stage = [&](int u){
    int tileA; const char* Wk;
    if (u <= L-2){
      tileA = q >> u;                        // chain: k = u+2
      Wk = W2fb + (size_t)(u+2)*8192;
    } else {
      int d = u - (L-1);
      tileA = (d==0) ? 2*q : (d==1) ? 4*q : (d==2) ? 4*q+1
            : (d==3) ? 2*q+1 : (d==4) ? 4*q+2 : 4*q+3;
      Wk = (d==0 || d==3) ? (W2fb + 8192) : W2fb;   // W2[1] : W2[0]
    }
    const char* Ht = Hb + (size_t)tileA*32768;
    char* Ab = As + (u & 1)*8192;
    char* Bb = Bs + (u & 1)*8192;
    #pragma unroll
    for (int j = 0; j < 2; ++j){
      int piece = wid*2 + j;                 // A: 8 pieces x 64 rows x 16B
      gll16(Ht + piece*4096 + (slice*64 + lane)*16, Ab + piece*1024);
    }
    #pragma unroll
    for (int j = 0; j < 2; ++j){
      int c = wid*2 + j;                     // B: 8 chunks x 1KB
      gll16(Wk + c*1024 + lane*16, Bb + c*1024);
    }
  };

  stage(0);
  __syncthreads();                           // stage(0) ready

  FragA held0, held1;                        // held0 = mid0, held1 = last leaf

  for (int s = 0; s < S; ++s){
    if (s + 1 < S) stage(s + 1);             // issue next-tile loads first
    const char* Ab = As + (s & 1)*8192;
    const char* Bb = Bs + (s & 1)*8192;
    FragB bF; ld_bfragL(bF, Bb, lane);
    if (s <= L-2){
      FragA aF; ld_afragL(aF, Ab, wid, l15, kg);
      mstep(acc, aF, bF);
    } else {
      int d = s - (L-1);
      if (d == 0){
        ld_afragL(held0, Ab, wid, l15, kg);            // mid0
        mstep(acc, held0, bF);                         // +mid0 (W2[1])
      } else if (d == 1){
        ld_afragL(held1, Ab, wid, l15, kg);            // leaf0
        mstep(acc, held1, bF);                         // +leaf0 (W2[0])
        epi_mfma(acc, cbv, scr, w3a, dA0, dA1, l15, kg);
      } else if (d == 2){
        negA(held1); mstep(acc, held1, bF);            // -leaf0
        ld_afragL(held1, Ab, wid, l15, kg);            // leaf1
        mstep(acc, held1, bF);                         // +leaf1
        epi_mfma(acc, cbv, scr, w3a, dB0, dB1, l15, kg);
      } else if (d == 3){
        negA(held0); mstep(acc, held0, bF);            // -mid0 (W2[1])
        FragA aF; ld_afragL(aF, Ab, wid, l15, kg);     // mid1
        mstep(acc, aF, bF);                            // +mid1
      } else if (d == 4){
        negA(held1); mstep(acc, held1, bF);            // -leaf1 (W2[0])
        ld_afragL(held1, Ab, wid, l15, kg);            // leaf2
        mstep(acc, held1, bF);                         // +leaf2
        epi_mfma(acc, cbv, scr, w3a, dC0, dC1, l15, kg);
      } else {
        negA(held1); mstep(acc, held1, bF);            // -leaf2
        FragA aF; ld_afragL(aF, Ab, wid, l15, kg);     // leaf3
        mstep(acc, aF, bF);                            // +leaf3
        epi_mfma(acc, cbv, scr, w3a, dD0, dD1, l15, kg);
      }
    }
    __syncthreads();                         // stage(s+1) complete; buf reads done
  }

  // deferred y3 stores (outside the barrier loop)
  STORE_D(dA0, dA1, 4*q,     L)
  STORE_D(dB0, dB1, 4*q + 1, L)
  STORE_D(dC0, dC1, 4*q + 2, L)
  STORE_D(dD0, dD1, 4*q + 3, L)
}

// ---------------- K3: block = quad of p (4i..4i+3), thread = b ---------------
__global__ __launch_bounds__(256) void k_scatter(const float* __restrict__ y3,
    const float* __restrict__ cb3, const float* __restrict__ w3h20,
    float* __restrict__ out){
  int i = blockIdx.x;                  // 512 quads
  int b = threadIdx.x;
  float4 o[4];
  #pragma unroll
  for (int c = 0; c < 4; ++c){
    int p = i*4 + c;
    int lp = levelof(p);
    float s0 = cb3[(lp+1)*2]     + w3h20[(lp+1)*2];
    float s1 = cb3[(lp+1)*2 + 1] + w3h20[(lp+1)*2 + 1];
    for (int k = 0; k <= lp; ++k){
      int pi = (4096 - (4096 >> k)) + (p >> k);
      float2 v = *(const float2*)(y3 + ((size_t)pi*256 + b)*2);
      s0 += v.x; s1 += v.y;
    }
    if (p == 0){
      o[c].x = cb3[0] + w3h20[0];
      o[c].y = cb3[1] + w3h20[1];
      o[c].z = s0; o[c].w = s1;
    } else {
      o[c].x = s0; o[c].y = s1; o[c].z = s0; o[c].w = s1;
    }
  }
  float4* dst = (float4*)(out + (size_t)b*8192 + (size_t)i*16);
  #pragma unroll
  for (int c = 0; c < 4; ++c) dst[c] = o[c];
}

extern "C" void kernel_launch(void* const* d_in, const int* in_sizes, int n_in,
                              void* d_out, int out_size, void* d_ws, size_t ws_size,
                              hipStream_t stream){
  const float* x  = (const float*)d_in[0];
  const float* W1 = (const float*)d_in[1];
  const float* b1 = (const float*)d_in[2];
  const float* W2 = (const float*)d_in[3];
  const float* b2 = (const float*)d_in[4];
  const float* W3 = (const float*)d_in[5];
  const float* b3 = (const float*)d_in[6];
  float* out = (float*)d_out;
  char* ws = (char*)d_ws;

  unsigned short* W2f   = (unsigned short*)(ws + 0);          //   106,496
  unsigned short* W1f   = (unsigned short*)(ws + 106496);     //     4,096
  unsigned short* W3Af  = (unsigned short*)(ws + 110592);     //     4,096
  float* cb1   = (float*)(ws + 114688);                       //     3,328
  float* cb2   = (float*)(ws + 118016);                       //     3,328
  float* cb3   = (float*)(ws + 121344);                       //       128
  float* w3h20 = (float*)(ws + 121472);                       //       128
  float* xT    = (float*)(ws + 121600);                       // 8,388,608
  unsigned short* H = (unsigned short*)(ws + 8510208);        // 67,108,864
  float* y3    = (float*)(ws + 75619072);                     // 8,386,560  [pair][b][2]
  // total 84,005,632 B

  hipLaunchKernelGGL(k_prep,    dim3(29),   dim3(256), 0, stream, W2, W1, W3, b1, b2, b3, W2f, W1f, W3Af, cb1, cb2, cb3, w3h20);
  hipLaunchKernelGGL(k_xpose,   dim3(256),  dim3(256), 0, stream, x, xT);
  hipLaunchKernelGGL(k_GH,      dim3(2048), dim3(256), 0, stream, xT, W1f, cb1, H);
  hipLaunchKernelGGL(k_F12,     dim3(2048), dim3(256), 0, stream, H, W2f, W3Af, cb2, y3);
  hipLaunchKernelGGL(k_scatter, dim3(512),  dim3(256), 0, stream, y3, cb3, w3h20, out);
}

// Round 15
// 144.887 us; speedup vs baseline: 1.4817x; 1.4817x over previous
//
#include <hip/hip_runtime.h>

#define UNITS 4096
#define DEPTH 13
#define BATCH 256

typedef __attribute__((ext_vector_type(8))) short s16x8;
typedef __attribute__((ext_vector_type(4))) float f32x4;
typedef __attribute__((ext_vector_type(4))) int   i32x4;

__device__ __forceinline__ unsigned short f2bf(float f){
  unsigned u = __builtin_bit_cast(unsigned, f);
  u += 0x7FFFu + ((u >> 16) & 1u);
  return (unsigned short)(u >> 16);
}
__device__ __forceinline__ int levelof(int j){ return j ? (32 - __clz(j)) : 0; }

struct FragA { s16x8 v[2]; };      // 8 VGPR: M=16 rows x K=64
struct FragB { s16x8 v[2][4]; };   // 32 VGPR: N=64 x K=64

// async global->LDS, 16B per lane, wave-uniform LDS base (+ lane*16 implicit)
__device__ __forceinline__ void gll16(const void* g, void* l){
  __builtin_amdgcn_global_load_lds(
      (const __attribute__((address_space(1))) unsigned int*)g,
      (__attribute__((address_space(3))) unsigned int*)l, 16, 0, 0);
}

// global-direct frag loads (q==0 path only)
__device__ __forceinline__ void load_afragG(FragA& f, const unsigned short* __restrict__ Hq,
                                            int rowbase, int l15, int kg){
  #pragma unroll
  for (int kk = 0; kk < 2; ++kk)
    f.v[kk] = *(const s16x8*)(Hq + ((size_t)((kk*4 + kg)*256 + rowbase + l15))*8);
}
__device__ __forceinline__ void load_bfragG(FragB& f, const unsigned short* __restrict__ Wf,
                                            int lane){
  #pragma unroll
  for (int kk = 0; kk < 2; ++kk)
    #pragma unroll
    for (int n = 0; n < 4; ++n)
      f.v[kk][n] = *(const s16x8*)(Wf + ((size_t)((kk*4 + n)*64 + lane))*8);
}
// LDS frag loads (A slice: [piece][64 rows]*16B; B: W2f layout)
__device__ __forceinline__ void ld_afragL(FragA& f, const char* Ab, int wid, int l15, int kg){
  #pragma unroll
  for (int kk = 0; kk < 2; ++kk)
    f.v[kk] = *(const s16x8*)(Ab + (kk*4 + kg)*1024 + (wid*16 + l15)*16);
}
__device__ __forceinline__ void ld_bfragL(FragB& f, const char* Bb, int lane){
  #pragma unroll
  for (int kk = 0; kk < 2; ++kk)
    #pragma unroll
    for (int n = 0; n < 4; ++n)
      f.v[kk][n] = *(const s16x8*)(Bb + ((kk*4 + n)*64 + lane)*16);
}
__device__ __forceinline__ void mstep(f32x4 acc[4], const FragA& A, const FragB& B){
  #pragma unroll
  for (int kk = 0; kk < 2; ++kk)
    #pragma unroll
    for (int n = 0; n < 4; ++n)
      acc[n] = __builtin_amdgcn_mfma_f32_16x16x32_bf16(A.v[kk], B.v[kk][n], acc[n], 0, 0, 0);
}
__device__ __forceinline__ void negA(FragA& A){
  const i32x4 sgn = {(int)0x80008000, (int)0x80008000, (int)0x80008000, (int)0x80008000};
  #pragma unroll
  for (int kk = 0; kk < 2; ++kk){
    i32x4 t = __builtin_bit_cast(i32x4, A.v[kk]);
    t ^= sgn;
    A.v[kk] = __builtin_bit_cast(s16x8, t);
  }
}

// 16-lane row reduction on the VALU pipe via DPP.
__device__ __forceinline__ float rowsum16(float s){
  int v, u;
  v = __builtin_bit_cast(int, s);
  u = __builtin_amdgcn_update_dpp(v, v, 0xB1, 0xF, 0xF, false);   // quad_perm [1,0,3,2]
  s += __builtin_bit_cast(float, u);
  v = __builtin_bit_cast(int, s);
  u = __builtin_amdgcn_update_dpp(v, v, 0x4E, 0xF, 0xF, false);   // quad_perm [2,3,0,1]
  s += __builtin_bit_cast(float, u);
  v = __builtin_bit_cast(int, s);
  u = __builtin_amdgcn_update_dpp(v, v, 0x141, 0xF, 0xF, false);  // row_half_mirror
  s += __builtin_bit_cast(float, u);
  v = __builtin_bit_cast(int, s);
  u = __builtin_amdgcn_update_dpp(v, v, 0x140, 0xF, 0xF, false);  // row_mirror
  s += __builtin_bit_cast(float, u);
  return s;
}

// epilogue (acc preserved): y3[(off(tt)+p)*256 + b] = W3[tt].relu(acc + cbv)
__device__ __forceinline__ void epilogue(const f32x4 acc[4], int p, int lp,
    const float cbv[4], const float* w3s,
    float* __restrict__ y3, int rowbase, int l15, int kg){
  int tmax = 11 - lp;
  for (int tt = 0; tt <= tmax; ++tt){
    float w30[4], w31[4];
    #pragma unroll
    for (int n = 0; n < 4; ++n){
      w30[n] = w3s[(tt*2 + 0)*64 + n*16 + l15];
      w31[n] = w3s[(tt*2 + 1)*64 + n*16 + l15];
    }
    int off = 4096 - (4096 >> tt);
    #pragma unroll
    for (int reg = 0; reg < 4; ++reg){
      float s0 = 0.f, s1 = 0.f;
      #pragma unroll
      for (int n = 0; n < 4; ++n){
        float hv = fmaxf(acc[n][reg] + cbv[n], 0.f);
        s0 = fmaf(w30[n], hv, s0);
        s1 = fmaf(w31[n], hv, s1);
      }
      s0 = rowsum16(s0);
      s1 = rowsum16(s1);
      if (l15 == 0){
        int b = rowbase + kg*4 + reg;
        float2 v; v.x = s0; v.y = s1;
        *(float2*)(y3 + ((size_t)(off + p)*256 + b)*2) = v;
      }
    }
  }
}

// ---------------- K0: prep: W2 -> frag-linear bf16, W1 B-frags, biases -------
__global__ __launch_bounds__(256) void k_prep(const float* __restrict__ W2,
    const float* __restrict__ W1, const float* __restrict__ W3,
    const float* __restrict__ b1, const float* __restrict__ b2, const float* __restrict__ b3,
    unsigned short* __restrict__ W2f, unsigned short* __restrict__ W1f,
    float* __restrict__ cb1, float* __restrict__ cb2, float* __restrict__ cb3,
    float* __restrict__ w3h20){
  int blk = blockIdx.x, t = threadIdx.x;
  if (blk < 26){
    int u = blk*256 + t;
    int lane = u & 63, c = (u >> 6) & 7, k = u >> 9;
    int n = c & 3, kk = c >> 2, l15 = lane & 15, kg = lane >> 4;
    s16x8 rr;
    #pragma unroll
    for (int e = 0; e < 8; ++e)
      rr[e] = (short)f2bf(W2[((size_t)(k*64 + n*16 + l15))*64 + kk*32 + kg*8 + e]);
    *(s16x8*)(W2f + (size_t)u*8) = rr;
  } else if (blk == 26){
    int n = t >> 6, lane = t & 63, l15 = lane & 15, kg = lane >> 4;
    int f = n*16 + l15;
    s16x8 r = {0,0,0,0,0,0,0,0};
    #pragma unroll
    for (int j = 0; j < 4; ++j){
      int m = kg*4 + j;
      if (m < DEPTH-1){
        r[2*j]   = (short)f2bf(W1[(m*64 + f)*2]);
        r[2*j+1] = (short)f2bf(W1[(m*64 + f)*2 + 1]);
      }
    }
    *(s16x8*)(W1f + (size_t)t*8) = r;
  } else {
    if (t < 64){
      float r = 0.f;
      cb1[t] = 0.f;
      for (int m = 1; m < DEPTH; ++m){ r += b1[(m-1)*64 + t]; cb1[m*64 + t] = r; }
      float r2 = 0.f;
      for (int m = 0; m < DEPTH; ++m){ r2 += b2[m*64 + t]; cb2[m*64 + t] = r2; }
    } else if (t < 66){
      int o = t - 64;
      float r = 0.f;
      for (int m = 0; m < DEPTH; ++m){ r += b3[m*2 + o]; cb3[m*2 + o] = r; }
    } else if (t >= 128 && t < 128 + DEPTH*2){
      int q = t - 128, tt = q >> 1, o = q & 1;
      float s = 0.f;
      for (int f = 0; f < 64; ++f)
        s = fmaf(W3[(tt*2 + o)*64 + f], fmaxf(b2[f], 0.f), s);
      w3h20[tt*2 + o] = s;
    }
  }
}

// ---------------- K0b: transpose x[b][j][2] -> xT[j][b][2] -------------------
__global__ __launch_bounds__(256) void k_xpose(const float* __restrict__ x,
                                               float* __restrict__ xT){
  __shared__ float2 tile[64][65];
  int jb = (blockIdx.x & 63) * 64;
  int bb = (blockIdx.x >> 6) * 64;
  int t = threadIdx.x;
  #pragma unroll
  for (int i = 0; i < 16; ++i){
    int idx = i*256 + t;
    int jj = idx & 63, b = idx >> 6;
    tile[jj][b] = *(const float2*)(x + (((size_t)(bb + b))*UNITS + jb + jj)*2);
  }
  __syncthreads();
  #pragma unroll
  for (int i = 0; i < 16; ++i){
    int idx = i*256 + t;
    int b = idx & 63, jj = idx >> 6;
    *(float2*)(xT + (((size_t)(jb + jj))*BATCH + bb + b)*2) = tile[jj][b];
  }
}

// ---------------- K1: H[p] = relu(sum_m W1[m].x[p>>m] + cb1[lvl(p)+1]) -------
__global__ __launch_bounds__(256) void k_GH(const float* __restrict__ xT,
    const unsigned short* __restrict__ W1f, const float* __restrict__ cb1,
    unsigned short* __restrict__ H){
  __shared__ unsigned short tile[BATCH*64];
  int p = blockIdx.x;
  int lvl = levelof(p);
  int t = threadIdx.x, wid = t >> 6, lane = t & 63, l15 = lane & 15, kg = lane >> 4;

  s16x8 af[4];
  #pragma unroll
  for (int m = 0; m < 4; ++m){
    int b = wid*64 + m*16 + l15;
    s16x8 r = {0,0,0,0,0,0,0,0};
    #pragma unroll
    for (int j = 0; j < 4; ++j){
      int mm = kg*4 + j;
      if (mm <= lvl){
        float2 xv = *(const float2*)(xT + ((size_t)(p >> mm)*BATCH + b)*2);
        r[2*j]   = (short)f2bf(xv.x);
        r[2*j+1] = (short)f2bf(xv.y);
      }
    }
    af[m] = r;
  }
  f32x4 acc[4][4];
  #pragma unroll
  for (int m = 0; m < 4; ++m)
    #pragma unroll
    for (int n = 0; n < 4; ++n) acc[m][n] = (f32x4){0.f,0.f,0.f,0.f};
  #pragma unroll
  for (int n = 0; n < 4; ++n){
    s16x8 bf = *(const s16x8*)(W1f + ((size_t)n*64 + lane)*8);
    #pragma unroll
    for (int m = 0; m < 4; ++m)
      acc[m][n] = __builtin_amdgcn_mfma_f32_16x16x32_bf16(af[m], bf, acc[m][n], 0, 0, 0);
  }
  int lvl1 = lvl + 1;
  float cbv[4];
  #pragma unroll
  for (int n = 0; n < 4; ++n) cbv[n] = cb1[lvl1*64 + n*16 + l15];
  #pragma unroll
  for (int m = 0; m < 4; ++m)
    #pragma unroll
    for (int n = 0; n < 4; ++n)
      #pragma unroll
      for (int i = 0; i < 4; ++i){
        int row = wid*64 + m*16 + kg*4 + i;
        int col = n*16 + l15;
        float v = fmaxf(acc[m][n][i] + cbv[n], 0.f);
        *(unsigned short*)((char*)tile + ((row*128 + col*2) ^ ((row & 7) << 4))) = f2bf(v);
      }
  __syncthreads();
  #pragma unroll
  for (int i = 0; i < 8; ++i){
    s16x8 v = *(const s16x8*)((const char*)tile + ((t*128 + i*16) ^ ((t & 7) << 4)));
    *(s16x8*)(H + (size_t)p*16384 + ((size_t)i*256 + t)*8) = v;
  }
}

// ---------------- K2: quad-DFS F, ring-3 LDS + counted vmcnt (T3/T4) ---------
// Identical compute to R13's k_F11; sync changed: every stage() issues exactly
// 4 gll16/thread (uniform), so vmcnt(8) after issuing stage(s+2) guarantees
// stage(s) retired (in-order, >=8 newer ops). Raw s_barrier, no vmcnt(0) drain
// mid-loop; tail uses vmcnt(0). Ring-3 gives loads ~2 compute-phases to land.
__global__ __launch_bounds__(256, 3) void k_F13(const unsigned short* __restrict__ H,
    const unsigned short* __restrict__ W2f, const float* __restrict__ cb2,
    const float* __restrict__ W3, float* __restrict__ y3){
  __shared__ char As[3*8192];
  __shared__ char Bs[3*8192];
  __shared__ float w3s[26*64];

  int bid = blockIdx.x;
  int slice = bid >> 9;                // 0..3 (64 batch rows each)
  int r = bid & 511;
  int q = 511 - ((r & 7)*64 + (r >> 3));   // deep-first, XCD-contiguous
  int t = threadIdx.x, wid = t >> 6, lane = t & 63, l15 = lane & 15, kg = lane >> 4;
  int rowbase = slice*64 + wid*16;

  const char* Hb   = (const char*)H;
  const char* W2fb = (const char*)W2f;

  // W3 -> LDS, then full sync (drains these loads before the ring starts)
  #pragma unroll
  for (int i = 0; i < 2; ++i){
    int idx = i*256 + t;
    if (idx < 416) ((float4*)w3s)[idx] = ((const float4*)W3)[idx];
  }
  __syncthreads();

  f32x4 acc[4];
  #pragma unroll
  for (int n = 0; n < 4; ++n) acc[n] = (f32x4){0.f, 0.f, 0.f, 0.f};

  if (q == 0){
    FragA A; FragB B;
    for (int p = 0; p < 4; ++p){
      int lp = levelof(p);
      float cbv[4];
      #pragma unroll
      for (int n = 0; n < 4; ++n) cbv[n] = cb2[(lp+1)*64 + n*16 + l15];
      #pragma unroll
      for (int n = 0; n < 4; ++n) acc[n] = (f32x4){0.f, 0.f, 0.f, 0.f};
      for (int k = 0; k <= lp; ++k){
        load_bfragG(B, W2f + (size_t)k*4096, lane);
        load_afragG(A, H + (size_t)(p >> k)*16384, rowbase, l15, kg);
        mstep(acc, A, B);
      }
      epilogue(acc, p, lp, cbv, w3s, y3, rowbase, l15, kg);
    }
    return;
  }

  const int L = levelof(q) + 2;        // leaf level, 2..11
  const int S = L + 5;                 // (L-1) chain steps + 6 DFS steps
  float cbv[4];
  #pragma unroll
  for (int n = 0; n < 4; ++n) cbv[n] = cb2[(L+1)*64 + n*16 + l15];

  auto stage = [&](int u){
    int tileA; const char* Wk;
    if (u <= L-2){
      tileA = q >> u;                        // chain: k = u+2
      Wk = W2fb + (size_t)(u+2)*8192;
    } else {
      int d = u - (L-1);
      tileA = (d==0) ? 2*q : (d==1) ? 4*q : (d==2) ? 4*q+1
            : (d==3) ? 2*q+1 : (d==4) ? 4*q+2 : 4*q+3;
      Wk = (d==0 || d==3) ? (W2fb + 8192) : W2fb;   // W2[1] : W2[0]
    }
    const char* Ht = Hb + (size_t)tileA*32768;
    int slot = u % 3;
    char* Ab = As + slot*8192;
    char* Bb = Bs + slot*8192;
    #pragma unroll
    for (int j = 0; j < 2; ++j){
      int piece = wid*2 + j;                 // A: 8 pieces x 64 rows x 16B
      gll16(Ht + piece*4096 + (slice*64 + lane)*16, Ab + piece*1024);
    }
    #pragma unroll
    for (int j = 0; j < 2; ++j){
      int c = wid*2 + j;                     // B: 8 chunks x 1KB
      gll16(Wk + c*1024 + lane*16, Bb + c*1024);
    }
  };

  stage(0);
  stage(1);

  FragA held0, held1;                        // held0 = mid0, held1 = last leaf

  for (int s = 0; s < S; ++s){
    if (s + 2 < S){
      stage(s + 2);
      asm volatile("s_waitcnt vmcnt(8)" ::: "memory");   // stage(s) retired
    } else {
      asm volatile("s_waitcnt vmcnt(0)" ::: "memory");   // tail: full drain
    }
    __builtin_amdgcn_s_barrier();            // all threads' stage(s) visible
    __builtin_amdgcn_sched_barrier(0);

    int slot = s % 3;
    const char* Ab = As + slot*8192;
    const char* Bb = Bs + slot*8192;
    FragB bF; ld_bfragL(bF, Bb, lane);
    if (s <= L-2){
      FragA aF; ld_afragL(aF, Ab, wid, l15, kg);
      mstep(acc, aF, bF);
    } else {
      int d = s - (L-1);
      if (d == 0){
        ld_afragL(held0, Ab, wid, l15, kg);            // mid0
        mstep(acc, held0, bF);                         // +mid0 (W2[1])
      } else if (d == 1){
        ld_afragL(held1, Ab, wid, l15, kg);            // leaf0
        mstep(acc, held1, bF);                         // +leaf0 (W2[0])
        epilogue(acc, 4*q, L, cbv, w3s, y3, rowbase, l15, kg);
      } else if (d == 2){
        negA(held1); mstep(acc, held1, bF);            // -leaf0
        ld_afragL(held1, Ab, wid, l15, kg);            // leaf1
        mstep(acc, held1, bF);                         // +leaf1
        epilogue(acc, 4*q + 1, L, cbv, w3s, y3, rowbase, l15, kg);
      } else if (d == 3){
        negA(held0); mstep(acc, held0, bF);            // -mid0 (W2[1])
        FragA aF; ld_afragL(aF, Ab, wid, l15, kg);     // mid1
        mstep(acc, aF, bF);                            // +mid1
      } else if (d == 4){
        negA(held1); mstep(acc, held1, bF);            // -leaf1 (W2[0])
        ld_afragL(held1, Ab, wid, l15, kg);            // leaf2
        mstep(acc, held1, bF);                         // +leaf2
        epilogue(acc, 4*q + 2, L, cbv, w3s, y3, rowbase, l15, kg);
      } else {
        negA(held1); mstep(acc, held1, bF);            // -leaf2
        FragA aF; ld_afragL(aF, Ab, wid, l15, kg);     // leaf3
        mstep(acc, aF, bF);                            // +leaf3
        epilogue(acc, 4*q + 3, L, cbv, w3s, y3, rowbase, l15, kg);
      }
    }
    __builtin_amdgcn_sched_barrier(0);
    __builtin_amdgcn_s_barrier();            // buf-s reads done before stage(s+3)
  }
}

// ---------------- K3: block = quad of p (4i..4i+3), thread = b ---------------
__global__ __launch_bounds__(256) void k_scatter(const float* __restrict__ y3,
    const float* __restrict__ cb3, const float* __restrict__ w3h20,
    float* __restrict__ out){
  int i = blockIdx.x;                  // 512 quads
  int b = threadIdx.x;
  float4 o[4];
  #pragma unroll
  for (int c = 0; c < 4; ++c){
    int p = i*4 + c;
    int lp = levelof(p);
    float s0 = cb3[(lp+1)*2]     + w3h20[(lp+1)*2];
    float s1 = cb3[(lp+1)*2 + 1] + w3h20[(lp+1)*2 + 1];
    for (int k = 0; k <= lp; ++k){
      int pi = (4096 - (4096 >> k)) + (p >> k);
      float2 v = *(const float2*)(y3 + ((size_t)pi*256 + b)*2);
      s0 += v.x; s1 += v.y;
    }
    if (p == 0){
      o[c].x = cb3[0] + w3h20[0];
      o[c].y = cb3[1] + w3h20[1];
      o[c].z = s0; o[c].w = s1;
    } else {
      o[c].x = s0; o[c].y = s1; o[c].z = s0; o[c].w = s1;
    }
  }
  float4* dst = (float4*)(out + (size_t)b*8192 + (size_t)i*16);
  #pragma unroll
  for (int c = 0; c < 4; ++c) dst[c] = o[c];
}

extern "C" void kernel_launch(void* const* d_in, const int* in_sizes, int n_in,
                              void* d_out, int out_size, void* d_ws, size_t ws_size,
                              hipStream_t stream){
  const float* x  = (const float*)d_in[0];
  const float* W1 = (const float*)d_in[1];
  const float* b1 = (const float*)d_in[2];
  const float* W2 = (const float*)d_in[3];
  const float* b2 = (const float*)d_in[4];
  const float* W3 = (const float*)d_in[5];
  const float* b3 = (const float*)d_in[6];
  float* out = (float*)d_out;
  char* ws = (char*)d_ws;

  unsigned short* W2f   = (unsigned short*)(ws + 0);          //   106,496
  unsigned short* W1f   = (unsigned short*)(ws + 106496);     //     4,096
  float* cb1   = (float*)(ws + 110592);                       //     3,328
  float* cb2   = (float*)(ws + 113920);                       //     3,328
  float* cb3   = (float*)(ws + 117248);                       //       128
  float* w3h20 = (float*)(ws + 117376);                       //       128
  float* xT    = (float*)(ws + 117504);                       // 8,388,608
  unsigned short* H = (unsigned short*)(ws + 8506112);        // 67,108,864
  float* y3    = (float*)(ws + 75614976);                     // 8,386,560  [pair][b][2]
  // total 84,001,536 B

  hipLaunchKernelGGL(k_prep,    dim3(28),   dim3(256), 0, stream, W2, W1, W3, b1, b2, b3, W2f, W1f, cb1, cb2, cb3, w3h20);
  hipLaunchKernelGGL(k_xpose,   dim3(256),  dim3(256), 0, stream, x, xT);
  hipLaunchKernelGGL(k_GH,      dim3(2048), dim3(256), 0, stream, xT, W1f, cb1, H);
  hipLaunchKernelGGL(k_F13,     dim3(2048), dim3(256), 0, stream, H, W2f, cb2, W3, y3);
  hipLaunchKernelGGL(k_scatter, dim3(512),  dim3(256), 0, stream, y3, cb3, w3h20, out);
}

// Round 16
// 122.602 us; speedup vs baseline: 1.7510x; 1.1818x over previous
//
#include <hip/hip_runtime.h>

#define UNITS 4096
#define DEPTH 13
#define BATCH 256

typedef __attribute__((ext_vector_type(8))) short s16x8;
typedef __attribute__((ext_vector_type(4))) float f32x4;
typedef __attribute__((ext_vector_type(4))) int   i32x4;

__device__ __forceinline__ unsigned short f2bf(float f){
  unsigned u = __builtin_bit_cast(unsigned, f);
  u += 0x7FFFu + ((u >> 16) & 1u);
  return (unsigned short)(u >> 16);
}
__device__ __forceinline__ int levelof(int j){ return j ? (32 - __clz(j)) : 0; }

struct FragA { s16x8 v[2]; };      // 8 VGPR: M=16 rows x K=64
struct FragB { s16x8 v[2][4]; };   // 32 VGPR: N=64 x K=64

// async global->LDS, 16B per lane, wave-uniform LDS base (+ lane*16 implicit)
__device__ __forceinline__ void gll16(const void* g, void* l){
  __builtin_amdgcn_global_load_lds(
      (const __attribute__((address_space(1))) unsigned int*)g,
      (__attribute__((address_space(3))) unsigned int*)l, 16, 0, 0);
}

// global-direct frag loads (q==0 path only)
__device__ __forceinline__ void load_afragG(FragA& f, const unsigned short* __restrict__ Hq,
                                            int rowbase, int l15, int kg){
  #pragma unroll
  for (int kk = 0; kk < 2; ++kk)
    f.v[kk] = *(const s16x8*)(Hq + ((size_t)((kk*4 + kg)*256 + rowbase + l15))*8);
}
__device__ __forceinline__ void load_bfragG(FragB& f, const unsigned short* __restrict__ Wf,
                                            int lane){
  #pragma unroll
  for (int kk = 0; kk < 2; ++kk)
    #pragma unroll
    for (int n = 0; n < 4; ++n)
      f.v[kk][n] = *(const s16x8*)(Wf + ((size_t)((kk*4 + n)*64 + lane))*8);
}
// LDS frag loads (A slice: [piece][64 rows]*16B; B: W2f layout)
__device__ __forceinline__ void ld_afragL(FragA& f, const char* Ab, int wid, int l15, int kg){
  #pragma unroll
  for (int kk = 0; kk < 2; ++kk)
    f.v[kk] = *(const s16x8*)(Ab + (kk*4 + kg)*1024 + (wid*16 + l15)*16);
}
__device__ __forceinline__ void ld_bfragL(FragB& f, const char* Bb, int lane){
  #pragma unroll
  for (int kk = 0; kk < 2; ++kk)
    #pragma unroll
    for (int n = 0; n < 4; ++n)
      f.v[kk][n] = *(const s16x8*)(Bb + ((kk*4 + n)*64 + lane)*16);
}
__device__ __forceinline__ void mstep(f32x4 acc[4], const FragA& A, const FragB& B){
  #pragma unroll
  for (int kk = 0; kk < 2; ++kk)
    #pragma unroll
    for (int n = 0; n < 4; ++n)
      acc[n] = __builtin_amdgcn_mfma_f32_16x16x32_bf16(A.v[kk], B.v[kk][n], acc[n], 0, 0, 0);
}
__device__ __forceinline__ void negA(FragA& A){
  const i32x4 sgn = {(int)0x80008000, (int)0x80008000, (int)0x80008000, (int)0x80008000};
  #pragma unroll
  for (int kk = 0; kk < 2; ++kk){
    i32x4 t = __builtin_bit_cast(i32x4, A.v[kk]);
    t ^= sgn;
    A.v[kk] = __builtin_bit_cast(s16x8, t);
  }
}

// MFMA epilogue (immediate stores, no deferral):
// h2 = relu(acc+cbv) -> per-wave LDS scratch (k_GH-style XOR swizzle, 16B-chunk
// consistent) -> 2x ds_read_b128 B-frags -> 4 MFMAs vs register W3 A-frags ->
// guarded scalar stores to y3[pair][b][2].
__device__ __forceinline__ void epi2(const f32x4 acc[4], const float cbv[4],
    char* scr, const s16x8 (&w3a)[2][2], float* __restrict__ y3,
    int p, int lp, int rowbase, int l15, int kg){
  #pragma unroll
  for (int n = 0; n < 4; ++n)
    #pragma unroll
    for (int reg = 0; reg < 4; ++reg){
      float hv = fmaxf(acc[n][reg] + cbv[n], 0.f);
      int row = kg*4 + reg;
      int byte = (row*128 + (n*16 + l15)*2) ^ ((row & 7) << 4);
      *(unsigned short*)(scr + byte) = f2bf(hv);
    }
  asm volatile("s_waitcnt lgkmcnt(0)" ::: "memory");
  __builtin_amdgcn_sched_barrier(0);
  s16x8 b0 = *(const s16x8*)(scr + ((l15*128 + (      kg*8)*2) ^ ((l15 & 7) << 4)));
  s16x8 b1 = *(const s16x8*)(scr + ((l15*128 + (32 +  kg*8)*2) ^ ((l15 & 7) << 4)));
  f32x4 d0 = {0,0,0,0}, d1 = {0,0,0,0};
  d0 = __builtin_amdgcn_mfma_f32_16x16x32_bf16(w3a[0][0], b0, d0, 0, 0, 0);
  d0 = __builtin_amdgcn_mfma_f32_16x16x32_bf16(w3a[1][0], b1, d0, 0, 0, 0);
  d1 = __builtin_amdgcn_mfma_f32_16x16x32_bf16(w3a[0][1], b0, d1, 0, 0, 0);
  d1 = __builtin_amdgcn_mfma_f32_16x16x32_bf16(w3a[1][1], b1, d1, 0, 0, 0);
  int cnt = 2*(12 - lp);
  #pragma unroll
  for (int reg = 0; reg < 4; ++reg){
    int tt0 = kg*4 + reg;
    if (tt0 < cnt){
      int tt = tt0 >> 1, o = tt0 & 1;
      y3[((size_t)((4096 - (4096 >> tt)) + p)*256 + rowbase + l15)*2 + o] = d0[reg];
    }
    int tt1 = 16 + kg*4 + reg;
    if (tt1 < cnt){
      int tt = tt1 >> 1, o = tt1 & 1;
      y3[((size_t)((4096 - (4096 >> tt)) + p)*256 + rowbase + l15)*2 + o] = d1[reg];
    }
  }
}

// ---------------- K0: prep: W2f, W1f, W3 A-frags, cumulative biases ----------
__global__ __launch_bounds__(256) void k_prep(const float* __restrict__ W2,
    const float* __restrict__ W1, const float* __restrict__ W3,
    const float* __restrict__ b1, const float* __restrict__ b2, const float* __restrict__ b3,
    unsigned short* __restrict__ W2f, unsigned short* __restrict__ W1f,
    unsigned short* __restrict__ W3Af,
    float* __restrict__ cb1, float* __restrict__ cb2, float* __restrict__ cb3,
    float* __restrict__ w3h20){
  int blk = blockIdx.x, t = threadIdx.x;
  if (blk < 26){
    int u = blk*256 + t;
    int lane = u & 63, c = (u >> 6) & 7, k = u >> 9;
    int n = c & 3, kk = c >> 2, l15 = lane & 15, kg = lane >> 4;
    s16x8 rr;
    #pragma unroll
    for (int e = 0; e < 8; ++e)
      rr[e] = (short)f2bf(W2[((size_t)(k*64 + n*16 + l15))*64 + kk*32 + kg*8 + e]);
    *(s16x8*)(W2f + (size_t)u*8) = rr;
  } else if (blk == 26){
    int n = t >> 6, lane = t & 63, l15 = lane & 15, kg = lane >> 4;
    int f = n*16 + l15;
    s16x8 r = {0,0,0,0,0,0,0,0};
    #pragma unroll
    for (int j = 0; j < 4; ++j){
      int m = kg*4 + j;
      if (m < DEPTH-1){
        r[2*j]   = (short)f2bf(W1[(m*64 + f)*2]);
        r[2*j+1] = (short)f2bf(W1[(m*64 + f)*2 + 1]);
      }
    }
    *(s16x8*)(W1f + (size_t)t*8) = r;
  } else if (blk == 27){
    // W3 A-frags: row = tt' = tile*16 + l15 (0..25, zero-pad), k = kk*32+kg*8+e
    int lane = t & 63, tile = (t >> 6) & 1, kk = t >> 7;
    int l15 = lane & 15, kg = lane >> 4;
    int row = tile*16 + l15;
    s16x8 r = {0,0,0,0,0,0,0,0};
    if (row < 26){
      #pragma unroll
      for (int e = 0; e < 8; ++e)
        r[e] = (short)f2bf(W3[(size_t)row*64 + kk*32 + kg*8 + e]);
    }
    *(s16x8*)(W3Af + (size_t)t*8) = r;   // idx = ((kk*2+tile)*64 + lane)
  } else {
    if (t < 64){
      float r = 0.f;
      cb1[t] = 0.f;
      for (int m = 1; m < DEPTH; ++m){ r += b1[(m-1)*64 + t]; cb1[m*64 + t] = r; }
      float r2 = 0.f;
      for (int m = 0; m < DEPTH; ++m){ r2 += b2[m*64 + t]; cb2[m*64 + t] = r2; }
    } else if (t < 66){
      int o = t - 64;
      float r = 0.f;
      for (int m = 0; m < DEPTH; ++m){ r += b3[m*2 + o]; cb3[m*2 + o] = r; }
    } else if (t >= 128 && t < 128 + DEPTH*2){
      int q = t - 128, tt = q >> 1, o = q & 1;
      float s = 0.f;
      for (int f = 0; f < 64; ++f)
        s = fmaf(W3[(tt*2 + o)*64 + f], fmaxf(b2[f], 0.f), s);
      w3h20[tt*2 + o] = s;
    }
  }
}

// ---------------- K0b: transpose x[b][j][2] -> xT[j][b][2] -------------------
__global__ __launch_bounds__(256) void k_xpose(const float* __restrict__ x,
                                               float* __restrict__ xT){
  __shared__ float2 tile[64][65];
  int jb = (blockIdx.x & 63) * 64;
  int bb = (blockIdx.x >> 6) * 64;
  int t = threadIdx.x;
  #pragma unroll
  for (int i = 0; i < 16; ++i){
    int idx = i*256 + t;
    int jj = idx & 63, b = idx >> 6;
    tile[jj][b] = *(const float2*)(x + (((size_t)(bb + b))*UNITS + jb + jj)*2);
  }
  __syncthreads();
  #pragma unroll
  for (int i = 0; i < 16; ++i){
    int idx = i*256 + t;
    int b = idx & 63, jj = idx >> 6;
    *(float2*)(xT + (((size_t)(jb + jj))*BATCH + bb + b)*2) = tile[jj][b];
  }
}

// ---------------- K1: H[p] = relu(sum_m W1[m].x[p>>m] + cb1[lvl(p)+1]) -------
__global__ __launch_bounds__(256) void k_GH(const float* __restrict__ xT,
    const unsigned short* __restrict__ W1f, const float* __restrict__ cb1,
    unsigned short* __restrict__ H){
  __shared__ unsigned short tile[BATCH*64];
  int p = blockIdx.x;
  int lvl = levelof(p);
  int t = threadIdx.x, wid = t >> 6, lane = t & 63, l15 = lane & 15, kg = lane >> 4;

  s16x8 af[4];
  #pragma unroll
  for (int m = 0; m < 4; ++m){
    int b = wid*64 + m*16 + l15;
    s16x8 r = {0,0,0,0,0,0,0,0};
    #pragma unroll
    for (int j = 0; j < 4; ++j){
      int mm = kg*4 + j;
      if (mm <= lvl){
        float2 xv = *(const float2*)(xT + ((size_t)(p >> mm)*BATCH + b)*2);
        r[2*j]   = (short)f2bf(xv.x);
        r[2*j+1] = (short)f2bf(xv.y);
      }
    }
    af[m] = r;
  }
  f32x4 acc[4][4];
  #pragma unroll
  for (int m = 0; m < 4; ++m)
    #pragma unroll
    for (int n = 0; n < 4; ++n) acc[m][n] = (f32x4){0.f,0.f,0.f,0.f};
  #pragma unroll
  for (int n = 0; n < 4; ++n){
    s16x8 bf = *(const s16x8*)(W1f + ((size_t)n*64 + lane)*8);
    #pragma unroll
    for (int m = 0; m < 4; ++m)
      acc[m][n] = __builtin_amdgcn_mfma_f32_16x16x32_bf16(af[m], bf, acc[m][n], 0, 0, 0);
  }
  int lvl1 = lvl + 1;
  float cbv[4];
  #pragma unroll
  for (int n = 0; n < 4; ++n) cbv[n] = cb1[lvl1*64 + n*16 + l15];
  #pragma unroll
  for (int m = 0; m < 4; ++m)
    #pragma unroll
    for (int n = 0; n < 4; ++n)
      #pragma unroll
      for (int i = 0; i < 4; ++i){
        int row = wid*64 + m*16 + kg*4 + i;
        int col = n*16 + l15;
        float v = fmaxf(acc[m][n][i] + cbv[n], 0.f);
        *(unsigned short*)((char*)tile + ((row*128 + col*2) ^ ((row & 7) << 4))) = f2bf(v);
      }
  __syncthreads();
  #pragma unroll
  for (int i = 0; i < 8; ++i){
    s16x8 v = *(const s16x8*)((const char*)tile + ((t*128 + i*16) ^ ((t & 7) << 4)));
    *(s16x8*)(H + (size_t)p*16384 + ((size_t)i*256 + t)*8) = v;
  }
}

// ---------------- K2: quad-DFS F, ring-2 LDS (R13 sync) + MFMA epilogue ------
__global__ __launch_bounds__(256, 3) void k_F14(const unsigned short* __restrict__ H,
    const unsigned short* __restrict__ W2f, const unsigned short* __restrict__ W3Af,
    const float* __restrict__ cb2, float* __restrict__ y3){
  __shared__ char As[2*8192];
  __shared__ char Bs[2*8192];
  __shared__ char scr_all[4*2048];

  int bid = blockIdx.x;
  int slice = bid >> 9;                // 0..3 (64 batch rows each)
  int r = bid & 511;
  int q = 511 - ((r & 7)*64 + (r >> 3));   // deep-first, XCD-contiguous
  int t = threadIdx.x, wid = t >> 6, lane = t & 63, l15 = lane & 15, kg = lane >> 4;
  int rowbase = slice*64 + wid*16;
  char* scr = scr_all + wid*2048;

  const char* Hb   = (const char*)H;
  const char* W2fb = (const char*)W2f;

  // W3 A-frags held in registers
  s16x8 w3a[2][2];
  #pragma unroll
  for (int kk = 0; kk < 2; ++kk)
    #pragma unroll
    for (int tile = 0; tile < 2; ++tile)
      w3a[kk][tile] = *(const s16x8*)(W3Af + ((size_t)((kk*2 + tile)*64 + lane))*8);

  f32x4 acc[4];
  #pragma unroll
  for (int n = 0; n < 4; ++n) acc[n] = (f32x4){0.f, 0.f, 0.f, 0.f};

  if (q == 0){
    FragA A; FragB B;
    for (int p = 0; p < 4; ++p){
      int lp = levelof(p);
      float cbv[4];
      #pragma unroll
      for (int n = 0; n < 4; ++n) cbv[n] = cb2[(lp+1)*64 + n*16 + l15];
      #pragma unroll
      for (int n = 0; n < 4; ++n) acc[n] = (f32x4){0.f, 0.f, 0.f, 0.f};
      for (int k = 0; k <= lp; ++k){
        load_bfragG(B, W2f + (size_t)k*4096, lane);
        load_afragG(A, H + (size_t)(p >> k)*16384, rowbase, l15, kg);
        mstep(acc, A, B);
      }
      epi2(acc, cbv, scr, w3a, y3, p, lp, rowbase, l15, kg);
    }
    return;
  }

  const int L = levelof(q) + 2;        // leaf level, 2..11
  const int S = L + 5;                 // (L-1) chain steps + 6 DFS steps
  float cbv[4];
  #pragma unroll
  for (int n = 0; n < 4; ++n) cbv[n] = cb2[(L+1)*64 + n*16 + l15];

  auto stage = [&](int u){
    int tileA; const char* Wk;
    if (u <= L-2){
      tileA = q >> u;                        // chain: k = u+2
      Wk = W2fb + (size_t)(u+2)*8192;
    } else {
      int d = u - (L-1);
      tileA = (d==0) ? 2*q : (d==1) ? 4*q : (d==2) ? 4*q+1
            : (d==3) ? 2*q+1 : (d==4) ? 4*q+2 : 4*q+3;
      Wk = (d==0 || d==3) ? (W2fb + 8192) : W2fb;   // W2[1] : W2[0]
    }
    const char* Ht = Hb + (size_t)tileA*32768;
    char* Ab = As + (u & 1)*8192;
    char* Bb = Bs + (u & 1)*8192;
    #pragma unroll
    for (int j = 0; j < 2; ++j){
      int piece = wid*2 + j;                 // A: 8 pieces x 64 rows x 16B
      gll16(Ht + piece*4096 + (slice*64 + lane)*16, Ab + piece*1024);
    }
    #pragma unroll
    for (int j = 0; j < 2; ++j){
      int c = wid*2 + j;                     // B: 8 chunks x 1KB
      gll16(Wk + c*1024 + lane*16, Bb + c*1024);
    }
  };

  stage(0);
  __syncthreads();                           // stage(0) ready

  FragA held0, held1;                        // held0 = mid0, held1 = last leaf

  for (int s = 0; s < S; ++s){
    if (s + 1 < S) stage(s + 1);             // issue next-tile loads first
    const char* Ab = As + (s & 1)*8192;
    const char* Bb = Bs + (s & 1)*8192;
    FragB bF; ld_bfragL(bF, Bb, lane);
    if (s <= L-2){
      FragA aF; ld_afragL(aF, Ab, wid, l15, kg);
      mstep(acc, aF, bF);
    } else {
      int d = s - (L-1);
      if (d == 0){
        ld_afragL(held0, Ab, wid, l15, kg);            // mid0
        mstep(acc, held0, bF);                         // +mid0 (W2[1])
      } else if (d == 1){
        ld_afragL(held1, Ab, wid, l15, kg);            // leaf0
        mstep(acc, held1, bF);                         // +leaf0 (W2[0])
        epi2(acc, cbv, scr, w3a, y3, 4*q, L, rowbase, l15, kg);
      } else if (d == 2){
        negA(held1); mstep(acc, held1, bF);            // -leaf0
        ld_afragL(held1, Ab, wid, l15, kg);            // leaf1
        mstep(acc, held1, bF);                         // +leaf1
        epi2(acc, cbv, scr, w3a, y3, 4*q + 1, L, rowbase, l15, kg);
      } else if (d == 3){
        negA(held0); mstep(acc, held0, bF);            // -mid0 (W2[1])
        FragA aF; ld_afragL(aF, Ab, wid, l15, kg);     // mid1
        mstep(acc, aF, bF);                            // +mid1
      } else if (d == 4){
        negA(held1); mstep(acc, held1, bF);            // -leaf1 (W2[0])
        ld_afragL(held1, Ab, wid, l15, kg);            // leaf2
        mstep(acc, held1, bF);                         // +leaf2
        epi2(acc, cbv, scr, w3a, y3, 4*q + 2, L, rowbase, l15, kg);
      } else {
        negA(held1); mstep(acc, held1, bF);            // -leaf2
        FragA aF; ld_afragL(aF, Ab, wid, l15, kg);     // leaf3
        mstep(acc, aF, bF);                            // +leaf3
        epi2(acc, cbv, scr, w3a, y3, 4*q + 3, L, rowbase, l15, kg);
      }
    }
    __syncthreads();                         // stage(s+1) complete; buf reads done
  }
}

// ---------------- K3: block = quad of p (4i..4i+3), thread = b ---------------
__global__ __launch_bounds__(256) void k_scatter(const float* __restrict__ y3,
    const float* __restrict__ cb3, const float* __restrict__ w3h20,
    float* __restrict__ out){
  int i = blockIdx.x;                  // 512 quads
  int b = threadIdx.x;
  float4 o[4];
  #pragma unroll
  for (int c = 0; c < 4; ++c){
    int p = i*4 + c;
    int lp = levelof(p);
    float s0 = cb3[(lp+1)*2]     + w3h20[(lp+1)*2];
    float s1 = cb3[(lp+1)*2 + 1] + w3h20[(lp+1)*2 + 1];
    for (int k = 0; k <= lp; ++k){
      int pi = (4096 - (4096 >> k)) + (p >> k);
      float2 v = *(const float2*)(y3 + ((size_t)pi*256 + b)*2);
      s0 += v.x; s1 += v.y;
    }
    if (p == 0){
      o[c].x = cb3[0] + w3h20[0];
      o[c].y = cb3[1] + w3h20[1];
      o[c].z = s0; o[c].w = s1;
    } else {
      o[c].x = s0; o[c].y = s1; o[c].z = s0; o[c].w = s1;
    }
  }
  float4* dst = (float4*)(out + (size_t)b*8192 + (size_t)i*16);
  #pragma unroll
  for (int c = 0; c < 4; ++c) dst[c] = o[c];
}

extern "C" void kernel_launch(void* const* d_in, const int* in_sizes, int n_in,
                              void* d_out, int out_size, void* d_ws, size_t ws_size,
                              hipStream_t stream){
  const float* x  = (const float*)d_in[0];
  const float* W1 = (const float*)d_in[1];
  const float* b1 = (const float*)d_in[2];
  const float* W2 = (const float*)d_in[3];
  const float* b2 = (const float*)d_in[4];
  const float* W3 = (const float*)d_in[5];
  const float* b3 = (const float*)d_in[6];
  float* out = (float*)d_out;
  char* ws = (char*)d_ws;

  unsigned short* W2f   = (unsigned short*)(ws + 0);          //   106,496
  unsigned short* W1f   = (unsigned short*)(ws + 106496);     //     4,096
  unsigned short* W3Af  = (unsigned short*)(ws + 110592);     //     4,096
  float* cb1   = (float*)(ws + 114688);                       //     3,328
  float* cb2   = (float*)(ws + 118016);                       //     3,328
  float* cb3   = (float*)(ws + 121344);                       //       128
  float* w3h20 = (float*)(ws + 121472);                       //       128
  float* xT    = (float*)(ws + 121600);                       // 8,388,608
  unsigned short* H = (unsigned short*)(ws + 8510208);        // 67,108,864
  float* y3    = (float*)(ws + 75619072);                     // 8,386,560  [pair][b][2]
  // total 84,005,632 B

  hipLaunchKernelGGL(k_prep,    dim3(29),   dim3(256), 0, stream, W2, W1, W3, b1, b2, b3, W2f, W1f, W3Af, cb1, cb2, cb3, w3h20);
  hipLaunchKernelGGL(k_xpose,   dim3(256),  dim3(256), 0, stream, x, xT);
  hipLaunchKernelGGL(k_GH,      dim3(2048), dim3(256), 0, stream, xT, W1f, cb1, H);
  hipLaunchKernelGGL(k_F14,     dim3(2048), dim3(256), 0, stream, H, W2f, W3Af, cb2, y3);
  hipLaunchKernelGGL(k_scatter, dim3(512),  dim3(256), 0, stream, y3, cb3, w3h20, out);
}